// Round 1
// baseline (263.436 us; speedup 1.0000x reference)
//
#include <hip/hip_runtime.h>
#include <math.h>

#define N 8192
#define FIN 129
#define D 64
#define TEMP 10.0f

#define BI 64
#define BJ 64
#define JSPLIT 4
#define NJT ((N / JSPLIT) / BJ)   // 32 j-tiles per block

// ---------------- Kernel 1: q = mlp_q(x), k = mlp_k(x) ----------------
// grid N/4 blocks x 256 threads; one wave per row; lane = output dim.
__global__ __launch_bounds__(256) void k_mlp(
    const float* __restrict__ x,
    const float* __restrict__ Wq1, const float* __restrict__ bq1,
    const float* __restrict__ Wq2, const float* __restrict__ bq2,
    const float* __restrict__ Wk1, const float* __restrict__ bk1,
    const float* __restrict__ Wk2, const float* __restrict__ bk2,
    float* __restrict__ qo, float* __restrict__ ko)
{
    __shared__ float xs[4][FIN];
    __shared__ float hqs[4][D];
    __shared__ float hks[4][D];
    const int wave = threadIdx.x >> 6;
    const int lane = threadIdx.x & 63;
    const int row  = (blockIdx.x << 2) + wave;

    const float* xr = x + row * FIN;
    xs[wave][lane]      = xr[lane];
    xs[wave][64 + lane] = xr[64 + lane];       // 64+63=127 < 129, always valid
    if (lane == 0) xs[wave][128] = xr[128];
    __syncthreads();

    float aq = bq1[lane], ak = bk1[lane];
    for (int f = 0; f < FIN; ++f) {
        const float xv = xs[wave][f];
        aq = fmaf(xv, Wq1[f * D + lane], aq);
        ak = fmaf(xv, Wk1[f * D + lane], ak);
    }
    hqs[wave][lane] = fmaxf(aq, 0.f);
    hks[wave][lane] = fmaxf(ak, 0.f);
    __syncthreads();

    float oq = bq2[lane], ok = bk2[lane];
    for (int t = 0; t < D; ++t) {
        oq = fmaf(hqs[wave][t], Wq2[t * D + lane], oq);
        ok = fmaf(hks[wave][t], Wk2[t * D + lane], ok);
    }
    qo[row * D + lane] = oq;
    ko[row * D + lane] = ok;
}

// ---------------- Kernel 2: qkt tile into d_out + partial row-max ----------------
// grid (N/BI, JSPLIT) x 256 threads. Thread micro-tile 4x4.
// ti = tid>>4 (row dir, 16 groups), tj = tid&15 (col dir) -> coalesced stores.
__global__ __launch_bounds__(256) void k_qkt(
    const float* __restrict__ q, const float* __restrict__ k,
    float* __restrict__ qkt, float* __restrict__ mp)
{
    __shared__ float qsT[D][BI + 4];   // [64][68] transposed: qsT[d][i]
    __shared__ float ksT[D][BJ + 4];
    __shared__ float red[BI][16];

    const int tid = threadIdx.x;
    const int ti = tid >> 4;          // 0..15 (i dir)
    const int tj = tid & 15;          // 0..15 (j dir)
    const int i0 = blockIdx.x * BI;
    const int jbase = blockIdx.y * (N / JSPLIT);

    // stage q tile transposed (once)
    {
        const int dg = tid & 15, ir = tid >> 4;
        #pragma unroll
        for (int p = 0; p < 4; ++p) {
            const int i = p * 16 + ir;
            const float4 v = *reinterpret_cast<const float4*>(&q[(i0 + i) * D + 4 * dg]);
            qsT[4 * dg + 0][i] = v.x;
            qsT[4 * dg + 1][i] = v.y;
            qsT[4 * dg + 2][i] = v.z;
            qsT[4 * dg + 3][i] = v.w;
        }
    }

    float rmax[4] = {-INFINITY, -INFINITY, -INFINITY, -INFINITY};

    for (int jt = 0; jt < NJT; ++jt) {
        const int j0 = jbase + jt * BJ;
        __syncthreads();   // protects ksT (and, first iter, qsT staging)
        {
            const int dg = tid & 15, jr = tid >> 4;
            #pragma unroll
            for (int p = 0; p < 4; ++p) {
                const int j = p * 16 + jr;
                const float4 v = *reinterpret_cast<const float4*>(&k[(j0 + j) * D + 4 * dg]);
                ksT[4 * dg + 0][j] = v.x;
                ksT[4 * dg + 1][j] = v.y;
                ksT[4 * dg + 2][j] = v.z;
                ksT[4 * dg + 3][j] = v.w;
            }
        }
        __syncthreads();

        float acc[4][4] = {{0.f}};
        #pragma unroll 8
        for (int d = 0; d < D; ++d) {
            const float4 qa = *reinterpret_cast<const float4*>(&qsT[d][4 * ti]);
            const float4 kb = *reinterpret_cast<const float4*>(&ksT[d][4 * tj]);
            const float qv[4] = {qa.x, qa.y, qa.z, qa.w};
            const float kv[4] = {kb.x, kb.y, kb.z, kb.w};
            #pragma unroll
            for (int r = 0; r < 4; ++r)
                #pragma unroll
                for (int c = 0; c < 4; ++c)
                    acc[r][c] = fmaf(qv[r], kv[c], acc[r][c]);
        }

        #pragma unroll
        for (int r = 0; r < 4; ++r) {
            const float4 st = make_float4(acc[r][0], acc[r][1], acc[r][2], acc[r][3]);
            *reinterpret_cast<float4*>(&qkt[(long)(i0 + 4 * ti + r) * N + j0 + 4 * tj]) = st;
            const float mx = fmaxf(fmaxf(acc[r][0], acc[r][1]), fmaxf(acc[r][2], acc[r][3]));
            rmax[r] = fmaxf(rmax[r], mx);
        }
    }

    // reduce partial row-max across the 16 tj threads
    #pragma unroll
    for (int r = 0; r < 4; ++r) red[4 * ti + r][tj] = rmax[r];
    __syncthreads();
    if (tid < BI) {
        float m = red[tid][0];
        #pragma unroll
        for (int t = 1; t < 16; ++t) m = fmaxf(m, red[tid][t]);
        mp[blockIdx.y * N + i0 + tid] = m;
    }
}

// ---------------- Kernel 3: m[j] = max of partials; rinv[j] = TEMP/m[j] ----------------
__global__ __launch_bounds__(256) void k_rinv(const float* __restrict__ mp, float* __restrict__ rinv)
{
    const int i = blockIdx.x * 256 + threadIdx.x;
    const float m = fmaxf(fmaxf(mp[i], mp[N + i]), fmaxf(mp[2 * N + i], mp[3 * N + i]));
    rinv[i] = TEMP / m;
}

// ---------------- Kernel 4: in-place row softmax of scaled qkt ----------------
// grid N blocks x 256 threads; row in registers (8 float4/thread).
__global__ __launch_bounds__(256) void k_softmax(float* __restrict__ qkt, const float* __restrict__ rinv)
{
    const int row  = blockIdx.x;
    const int tid  = threadIdx.x;
    const int lane = tid & 63;
    const int wave = tid >> 6;

    float4* rowp = reinterpret_cast<float4*>(qkt + (long)row * N);
    const float4* rv = reinterpret_cast<const float4*>(rinv);

    __shared__ float redmax[4];
    __shared__ float redsum[4];

    float4 v[8];
    float lmax = -INFINITY;
    #pragma unroll
    for (int p = 0; p < 8; ++p) {
        float4 a = rowp[p * 256 + tid];
        const float4 r4 = rv[p * 256 + tid];
        a.x *= r4.x; a.y *= r4.y; a.z *= r4.z; a.w *= r4.w;
        v[p] = a;
        lmax = fmaxf(lmax, fmaxf(fmaxf(a.x, a.y), fmaxf(a.z, a.w)));
    }

    #pragma unroll
    for (int off = 32; off > 0; off >>= 1) lmax = fmaxf(lmax, __shfl_xor(lmax, off));
    if (lane == 0) redmax[wave] = lmax;
    __syncthreads();
    const float mx = fmaxf(fmaxf(redmax[0], redmax[1]), fmaxf(redmax[2], redmax[3]));

    float lsum = 0.f;
    #pragma unroll
    for (int p = 0; p < 8; ++p) {
        v[p].x = __expf(v[p].x - mx);
        v[p].y = __expf(v[p].y - mx);
        v[p].z = __expf(v[p].z - mx);
        v[p].w = __expf(v[p].w - mx);
        lsum += v[p].x + v[p].y + v[p].z + v[p].w;
    }
    #pragma unroll
    for (int off = 32; off > 0; off >>= 1) lsum += __shfl_xor(lsum, off);
    if (lane == 0) redsum[wave] = lsum;
    __syncthreads();
    const float inv = 1.f / (redsum[0] + redsum[1] + redsum[2] + redsum[3]);

    #pragma unroll
    for (int p = 0; p < 8; ++p) {
        float4 a = v[p];
        a.x *= inv; a.y *= inv; a.z *= inv; a.w *= inv;
        rowp[p * 256 + tid] = a;
    }
}

extern "C" void kernel_launch(void* const* d_in, const int* in_sizes, int n_in,
                              void* d_out, int out_size, void* d_ws, size_t ws_size,
                              hipStream_t stream)
{
    const float* x   = (const float*)d_in[0];
    const float* Wq1 = (const float*)d_in[1];
    const float* bq1 = (const float*)d_in[2];
    const float* Wq2 = (const float*)d_in[3];
    const float* bq2 = (const float*)d_in[4];
    const float* Wk1 = (const float*)d_in[5];
    const float* bk1 = (const float*)d_in[6];
    const float* Wk2 = (const float*)d_in[7];
    const float* bk2 = (const float*)d_in[8];

    float* out = (float*)d_out;           // holds qkt, then softmax result in place

    // workspace layout (floats): q[N*D], k[N*D], mp[JSPLIT*N], rinv[N] ~ 4.4 MB
    float* qbuf = (float*)d_ws;
    float* kbuf = qbuf + N * D;
    float* mp   = kbuf + N * D;
    float* rinv = mp + JSPLIT * N;

    k_mlp<<<N / 4, 256, 0, stream>>>(x, Wq1, bq1, Wq2, bq2, Wk1, bk1, Wk2, bk2, qbuf, kbuf);
    k_qkt<<<dim3(N / BI, JSPLIT), 256, 0, stream>>>(qbuf, kbuf, out, mp);
    k_rinv<<<N / 256, 256, 0, stream>>>(mp, rinv);
    k_softmax<<<N, 256, 0, stream>>>(out, rinv);
}

// Round 2
// 172.904 us; speedup vs baseline: 1.5236x; 1.5236x over previous
//
#include <hip/hip_runtime.h>
#include <math.h>

#define N 8192
#define FIN 129
#define D 64
#define TEMP 10.0f
#define SPLIT 16            // column splits for the stats passes

typedef _Float16 f16x8 __attribute__((ext_vector_type(8)));
typedef float    f32x4 __attribute__((ext_vector_type(4)));

#define MFMA16(A, B, C) __builtin_amdgcn_mfma_f32_16x16x32_f16((A), (B), (C), 0, 0, 0)

// ---------------- Kernel 1: q = mlp_q(x), k = mlp_k(x) -> f16 ----------------
__global__ __launch_bounds__(256) void k_mlp(
    const float* __restrict__ x,
    const float* __restrict__ Wq1, const float* __restrict__ bq1,
    const float* __restrict__ Wq2, const float* __restrict__ bq2,
    const float* __restrict__ Wk1, const float* __restrict__ bk1,
    const float* __restrict__ Wk2, const float* __restrict__ bk2,
    _Float16* __restrict__ qo, _Float16* __restrict__ ko)
{
    __shared__ float xs[4][FIN];
    __shared__ float hqs[4][D];
    __shared__ float hks[4][D];
    const int wave = threadIdx.x >> 6;
    const int lane = threadIdx.x & 63;
    const int row  = (blockIdx.x << 2) + wave;

    const float* xr = x + row * FIN;
    xs[wave][lane]      = xr[lane];
    xs[wave][64 + lane] = xr[64 + lane];
    if (lane == 0) xs[wave][128] = xr[128];
    __syncthreads();

    float aq = bq1[lane], ak = bk1[lane];
    for (int f = 0; f < FIN; ++f) {
        const float xv = xs[wave][f];
        aq = fmaf(xv, Wq1[f * D + lane], aq);
        ak = fmaf(xv, Wk1[f * D + lane], ak);
    }
    hqs[wave][lane] = fmaxf(aq, 0.f);
    hks[wave][lane] = fmaxf(ak, 0.f);
    __syncthreads();

    float oq = bq2[lane], ok = bk2[lane];
    for (int t = 0; t < D; ++t) {
        oq = fmaf(hqs[wave][t], Wq2[t * D + lane], oq);
        ok = fmaf(hks[wave][t], Wk2[t * D + lane], ok);
    }
    qo[row * D + lane] = (_Float16)oq;
    ko[row * D + lane] = (_Float16)ok;
}

// ---------------- Stats passes (MFMA, nothing large stored) ----------------
// MODE 0: per-row max of raw q@k^T          -> outM = mpart[SPLIT][N]
// MODE 1: per-row online softmax stats of (rinv[j] * q@k^T) -> Mpart, Lpart
// Block: 256 thr / 4 waves; wave owns 32 rows (2 row-frags); block sweeps N/SPLIT cols.
template<int MODE>
__global__ __launch_bounds__(256) void k_stats(
    const _Float16* __restrict__ q16, const _Float16* __restrict__ k16,
    const float* __restrict__ rinv,
    float* __restrict__ outM, float* __restrict__ outL)
{
    const int tid  = threadIdx.x;
    const int wave = tid >> 6;
    const int lane = tid & 63;
    const int lr   = lane & 15;
    const int lg   = lane >> 4;
    const int i0   = blockIdx.x * 128 + wave * 32;
    const int jbase = blockIdx.y * (N / SPLIT);

    f16x8 a[2][2];
    #pragma unroll
    for (int rf = 0; rf < 2; ++rf)
        #pragma unroll
        for (int kf = 0; kf < 2; ++kf)
            a[rf][kf] = *reinterpret_cast<const f16x8*>(
                &q16[(i0 + rf * 16 + lr) * D + kf * 32 + 8 * lg]);

    f32x4 mx[2], sm[2];
    #pragma unroll
    for (int rf = 0; rf < 2; ++rf)
        #pragma unroll
        for (int e = 0; e < 4; ++e) { mx[rf][e] = -INFINITY; sm[rf][e] = 0.f; }

    for (int cf = 0; cf < (N / SPLIT) / 16; ++cf) {
        const int j0 = jbase + cf * 16;
        const f16x8 b0 = *reinterpret_cast<const f16x8*>(&k16[(j0 + lr) * D + 8 * lg]);
        const f16x8 b1 = *reinterpret_cast<const f16x8*>(&k16[(j0 + lr) * D + 32 + 8 * lg]);
        float r = 1.f;
        if (MODE) r = rinv[j0 + lr];   // per-lane column scale (col = lane&15)
        #pragma unroll
        for (int rf = 0; rf < 2; ++rf) {
            f32x4 acc = {0.f, 0.f, 0.f, 0.f};
            acc = MFMA16(a[rf][0], b0, acc);
            acc = MFMA16(a[rf][1], b1, acc);
            if (MODE == 0) {
                #pragma unroll
                for (int e = 0; e < 4; ++e) mx[rf][e] = fmaxf(mx[rf][e], acc[e]);
            } else {
                #pragma unroll
                for (int e = 0; e < 4; ++e) {
                    const float s  = acc[e] * r;
                    const float nm = fmaxf(mx[rf][e], s);
                    sm[rf][e] = sm[rf][e] * __expf(mx[rf][e] - nm) + __expf(s - nm);
                    mx[rf][e] = nm;
                }
            }
        }
    }

    // merge across the 16 lanes sharing a row group (C layout: row=(lane>>4)*4+e, col=lane&15)
    #pragma unroll
    for (int rf = 0; rf < 2; ++rf) {
        #pragma unroll
        for (int off = 1; off < 16; off <<= 1) {
            #pragma unroll
            for (int e = 0; e < 4; ++e) {
                const float om = __shfl_xor(mx[rf][e], off);
                if (MODE) {
                    const float os = __shfl_xor(sm[rf][e], off);
                    const float nm = fmaxf(mx[rf][e], om);
                    sm[rf][e] = sm[rf][e] * __expf(mx[rf][e] - nm) + os * __expf(om - nm);
                    mx[rf][e] = nm;
                } else {
                    mx[rf][e] = fmaxf(mx[rf][e], om);
                }
            }
        }
        if (lr == 0) {
            #pragma unroll
            for (int e = 0; e < 4; ++e) {
                const int row = i0 + rf * 16 + lg * 4 + e;
                outM[blockIdx.y * N + row] = mx[rf][e];
                if (MODE) outL[blockIdx.y * N + row] = sm[rf][e];
            }
        }
    }
}

// ---------------- rinv[j] = TEMP / max_s mpart[s][j] ----------------
__global__ __launch_bounds__(256) void k_fin1(const float* __restrict__ mp, float* __restrict__ rinv)
{
    const int j = blockIdx.x * 256 + threadIdx.x;
    float m = mp[j];
    #pragma unroll
    for (int s = 1; s < SPLIT; ++s) m = fmaxf(m, mp[s * N + j]);
    rinv[j] = TEMP / m;
}

// ---------------- M[i], Linv[i] from split partials ----------------
__global__ __launch_bounds__(256) void k_fin2(
    const float* __restrict__ Mp, const float* __restrict__ Lp,
    float* __restrict__ Mrow, float* __restrict__ Linv)
{
    const int i = blockIdx.x * 256 + threadIdx.x;
    float M = Mp[i];
    #pragma unroll
    for (int s = 1; s < SPLIT; ++s) M = fmaxf(M, Mp[s * N + i]);
    float L = 0.f;
    #pragma unroll
    for (int s = 0; s < SPLIT; ++s) L += Lp[s * N + i] * __expf(Mp[s * N + i] - M);
    Mrow[i] = M;
    Linv[i] = 1.f / L;
}

// ---------------- Final pass: recompute scores, write softmax ----------------
// Block 256 thr / 4 waves; tile 128 rows x 128 cols. Grid (64,64).
__global__ __launch_bounds__(256) void k_write(
    const _Float16* __restrict__ q16, const _Float16* __restrict__ k16,
    const float* __restrict__ rinv, const float* __restrict__ Mrow,
    const float* __restrict__ Linv, float* __restrict__ out)
{
    const int tid  = threadIdx.x;
    const int wave = tid >> 6;
    const int lane = tid & 63;
    const int lr   = lane & 15;
    const int lg   = lane >> 4;
    const int i0   = blockIdx.x * 128 + wave * 32;
    const int j0b  = blockIdx.y * 128;

    f16x8 a[2][2];
    float Mv[2][4], Lv[2][4];
    #pragma unroll
    for (int rf = 0; rf < 2; ++rf) {
        #pragma unroll
        for (int kf = 0; kf < 2; ++kf)
            a[rf][kf] = *reinterpret_cast<const f16x8*>(
                &q16[(i0 + rf * 16 + lr) * D + kf * 32 + 8 * lg]);
        #pragma unroll
        for (int e = 0; e < 4; ++e) {
            const int row = i0 + rf * 16 + lg * 4 + e;
            Mv[rf][e] = Mrow[row];
            Lv[rf][e] = Linv[row];
        }
    }

    #pragma unroll
    for (int cf = 0; cf < 8; ++cf) {
        const int j0 = j0b + cf * 16;
        const f16x8 b0 = *reinterpret_cast<const f16x8*>(&k16[(j0 + lr) * D + 8 * lg]);
        const f16x8 b1 = *reinterpret_cast<const f16x8*>(&k16[(j0 + lr) * D + 32 + 8 * lg]);
        const float r = rinv[j0 + lr];
        #pragma unroll
        for (int rf = 0; rf < 2; ++rf) {
            f32x4 acc = {0.f, 0.f, 0.f, 0.f};
            acc = MFMA16(a[rf][0], b0, acc);
            acc = MFMA16(a[rf][1], b1, acc);
            #pragma unroll
            for (int e = 0; e < 4; ++e) {
                const long row = i0 + rf * 16 + lg * 4 + e;
                out[row * N + j0 + lr] = __expf(acc[e] * r - Mv[rf][e]) * Lv[rf][e];
            }
        }
    }
}

extern "C" void kernel_launch(void* const* d_in, const int* in_sizes, int n_in,
                              void* d_out, int out_size, void* d_ws, size_t ws_size,
                              hipStream_t stream)
{
    const float* x   = (const float*)d_in[0];
    const float* Wq1 = (const float*)d_in[1];
    const float* bq1 = (const float*)d_in[2];
    const float* Wq2 = (const float*)d_in[3];
    const float* bq2 = (const float*)d_in[4];
    const float* Wk1 = (const float*)d_in[5];
    const float* bk1 = (const float*)d_in[6];
    const float* Wk2 = (const float*)d_in[7];
    const float* bk2 = (const float*)d_in[8];

    float* out = (float*)d_out;

    // workspace layout
    _Float16* q16 = (_Float16*)d_ws;                       // N*D f16 = 1 MB
    _Float16* k16 = q16 + (size_t)N * D;                   // 1 MB
    float* mpart  = (float*)(k16 + (size_t)N * D);         // SPLIT*N f32
    float* Mpart  = mpart + (size_t)SPLIT * N;
    float* Lpart  = Mpart + (size_t)SPLIT * N;
    float* rinv   = Lpart + (size_t)SPLIT * N;             // N
    float* Mrow   = rinv + N;                              // N
    float* Linv   = Mrow + N;                              // N

    k_mlp<<<N / 4, 256, 0, stream>>>(x, Wq1, bq1, Wq2, bq2, Wk1, bk1, Wk2, bk2, q16, k16);
    k_stats<0><<<dim3(N / 128, SPLIT), 256, 0, stream>>>(q16, k16, nullptr, mpart, nullptr);
    k_fin1<<<N / 256, 256, 0, stream>>>(mpart, rinv);
    k_stats<1><<<dim3(N / 128, SPLIT), 256, 0, stream>>>(q16, k16, rinv, Mpart, Lpart);
    k_fin2<<<N / 256, 256, 0, stream>>>(Mpart, Lpart, Mrow, Linv);
    k_write<<<dim3(N / 128, N / 128), 256, 0, stream>>>(q16, k16, rinv, Mrow, Linv, out);
}